// Round 5
// baseline (484.357 us; speedup 1.0000x reference)
//
#include <hip/hip_runtime.h>

#define HS   1024
#define SEQ  512
#define NBAT 64
#define INSZ 8
#define NM   4
#define DD   12
#define CH   16     // steps per P-chunk

#define ALPHA 0.1f
#define OMA   0.9f
#define SCL   (500.0f/1024.0f)
#define AS    (ALPHA*SCL)

// exp(2h) as exp2(GS*h) when native exp2 exists. A, B, ys all carry GS.
#if __has_builtin(__builtin_amdgcn_exp2f)
  #define GS 2.8853900817779268f      /* 2*log2(e) */
  #define EXPG(v) __builtin_amdgcn_exp2f(v)
#else
  #define GS 2.0f
  #define EXPG(v) __expf(v)
#endif

typedef float f2 __attribute__((ext_vector_type(2)));
typedef float f4 __attribute__((ext_vector_type(4)));
__device__ __forceinline__ f2 mk2(float a, float b){ f2 r; r.x=a; r.y=b; return r; }
__device__ __forceinline__ f2 splat2(float a){ return mk2(a,a); }
__device__ __forceinline__ f4 splat4(float a){ f4 r; r.x=a; r.y=a; r.z=a; r.w=a; return r; }
#if __has_builtin(__builtin_elementwise_fma)
__device__ __forceinline__ f2 fma2(f2 a, f2 b, f2 c){ return __builtin_elementwise_fma(a,b,c); }
__device__ __forceinline__ f4 fma4(f4 a, f4 b, f4 c){ return __builtin_elementwise_fma(a,b,c); }
#else
__device__ __forceinline__ f2 fma2(f2 a, f2 b, f2 c){
  f2 r; r.x=fmaf(a.x,b.x,c.x); r.y=fmaf(a.y,b.y,c.y); return r; }
__device__ __forceinline__ f4 fma4(f4 a, f4 b, f4 c){
  f4 r; r.x=fmaf(a.x,b.x,c.x); r.y=fmaf(a.y,b.y,c.y);
        r.z=fmaf(a.z,b.z,c.z); r.w=fmaf(a.w,b.w,c.w); return r; }
#endif

// DPP-based add: v += dpp_move(v). old=0 so masked/invalid lanes add 0.
#define DPP_ADD(v, ctrl, rmask, bmask) \
  v += __int_as_float(__builtin_amdgcn_update_dpp(0, __float_as_int(v), ctrl, rmask, bmask, true))

// Canonical gfx9 wave64 sum. Lane 63 holds the full 64-lane total afterwards.
__device__ __forceinline__ void wave64_sum2(float &a, float &b){
  DPP_ADD(a, 0x111, 0xf, 0xf); DPP_ADD(b, 0x111, 0xf, 0xf);  // row_shr:1
  DPP_ADD(a, 0x112, 0xf, 0xf); DPP_ADD(b, 0x112, 0xf, 0xf);  // row_shr:2
  DPP_ADD(a, 0x114, 0xf, 0xe); DPP_ADD(b, 0x114, 0xf, 0xe);  // row_shr:4
  DPP_ADD(a, 0x118, 0xf, 0xc); DPP_ADD(b, 0x118, 0xf, 0xc);  // row_shr:8
  DPP_ADD(a, 0x142, 0xa, 0xf); DPP_ADD(b, 0x142, 0xa, 0xf);  // row_bcast:15
  DPP_ADD(a, 0x143, 0xc, 0xf); DPP_ADD(b, 0x143, 0xc, 0xf);  // row_bcast:31
}
#define RD63(v) __int_as_float(__builtin_amdgcn_readlane(__float_as_int(v), 63))

// mixed[e] for unit i, e in [0,12).
__device__ __forceinline__ void mix_unit(int i, const float* __restrict__ eps,
                                         const float* __restrict__ means,
                                         const float* __restrict__ tril,
                                         const float* w, float* outm){
  float ep[NM][DD];
  #pragma unroll
  for (int k=0;k<NM;k++){
    const float4* p = (const float4*)(eps + (size_t)(k*HS + i)*DD);
    float4 r0=p[0], r1=p[1], r2=p[2];
    ep[k][0]=r0.x; ep[k][1]=r0.y; ep[k][2]=r0.z; ep[k][3]=r0.w;
    ep[k][4]=r1.x; ep[k][5]=r1.y; ep[k][6]=r1.z; ep[k][7]=r1.w;
    ep[k][8]=r2.x; ep[k][9]=r2.y; ep[k][10]=r2.z; ep[k][11]=r2.w;
  }
  #pragma unroll
  for (int e=0;e<DD;e++){
    float a = 0.f;
    #pragma unroll
    for (int k=0;k<NM;k++){
      float se = means[k*DD+e];
      #pragma unroll
      for (int d=0; d<e; d++) se = fmaf(ep[k][d], tril[(k*DD+e)*DD+d], se);
      float dg = fabsf(tril[(k*DD+e)*DD+e] - 1e-12f) + 1e-12f;
      se = fmaf(ep[k][e], dg, se);
      a = fmaf(w[k], se, a);
    }
    outm[e] = a;
  }
}

// Single-wave-per-batch scan, chunked. Phase A computes P[t][i] = I_i . Yg(t)
// into LDS one s-slice at a time (only 32 VGPRs of I live at once -> no
// spills); phase B is the serial scan reading its own lane's P back (in-order
// DS, no barriers) with a 1-step ds_read prefetch.
__global__ __launch_bounds__(64,1)
void rnn_scan(const float* __restrict__ x, const float* __restrict__ eps,
              const float* __restrict__ means, const float* __restrict__ tril,
              const float* __restrict__ mw, float* __restrict__ out)
{
  const int b    = blockIdx.x;
  const int lane = threadIdx.x;            // 64 threads = 1 wave, 16 units/lane

  __shared__ float xs[SEQ*INSZ];                 // 16 KB
  __shared__ f4    ys4[SEQ][2];                  // 16 KB: Yg(t), GS-scaled
  __shared__ f4    Pb[CH][4][64];                // 64 KB: P chunk, lane-contig
  __shared__ f4    Ivl[4][8][64];                // 32 KB: I cols, lane-contig
  __shared__ __align__(16) float outb[SEQ*10];   // 20 KB   (total 148 KB)

  // stage x[b] early; loads fly under the preprocessing below
  { const f4* xp=(const f4*)(x + (size_t)b*SEQ*INSZ);
    f4* xd=(f4*)xs;
    for (int idx=lane; idx<SEQ*INSZ/4; idx+=64) xd[idx]=xp[idx]; }

  float w[NM];
  { float s=0.f;
    #pragma unroll
    for (int k=0;k<NM;k++){ w[k]=fmaxf(mw[k],1e-6f); s+=w[k]; }
    float inv=1.0f/s;
    #pragma unroll
    for (int k=0;k<NM;k++) w[k]*=inv; }

  // ---- preprocess: units 16*lane + 4*s + j; pair p = 2s+(j>>1), comp j&1 ----
  f2 m0v[8], m1v[8], n0v[8], n1v[8];
  float sn0=0.f, sn1=0.f;
  #pragma unroll
  for (int s=0;s<4;s++){
    f4 Irow[8];
    #pragma unroll
    for (int j=0;j<4;j++){
      float mm[DD];
      mix_unit(16*lane + 4*s + j, eps, means, tril, w, mm);
      const int p = 2*s + (j>>1);
      if ((j&1)==0){ m0v[p].x=mm[0]; m1v[p].x=mm[1];
                     n0v[p].x=-2.f*mm[2]; n1v[p].x=-2.f*mm[3]; }
      else         { m0v[p].y=mm[0]; m1v[p].y=mm[1];
                     n0v[p].y=-2.f*mm[2]; n1v[p].y=-2.f*mm[3]; }
      sn0 += mm[2]; sn1 += mm[3];
      #pragma unroll
      for (int e=0;e<8;e++) Irow[e][j] = mm[4+e];
    }
    #pragma unroll
    for (int e=0;e<8;e++) Ivl[s][e][lane] = Irow[e];
  }
  wave64_sum2(sn0, sn1);
  const float N0 = RD63(sn0), N1 = RD63(sn1);

  __syncthreads();   // xs staged, Ivl written (1 wave: ~free)

  // ---- ys: Yg at START of step t (folds x_0..x_{t-1}); verified gemm_c order
  if (lane < 8){
    float* ysf = (float*)ys4;
    float Y = 0.f;
    const float AG = GS*ALPHA;
    for (int t=0;t<SEQ;t++){
      ysf[t*8+lane] = Y;
      Y = fmaf(OMA, Y, AG*xs[t*8+lane]);
    }
  }
  __syncthreads();

  const float CA = GS*AS;
  float A=0.f, Bst=0.f, o=0.f;

  #define STEP(T, TN, c0,c1,c2,c3, d0,d1,d2,d3) { \
    d0=Pb[TN][0][lane]; d1=Pb[TN][1][lane]; d2=Pb[TN][2][lane]; d3=Pb[TN][3][lane]; \
    f2 g[8]; \
    g[0]=mk2(c0.x,c0.y); g[1]=mk2(c0.z,c0.w); \
    g[2]=mk2(c1.x,c1.y); g[3]=mk2(c1.z,c1.w); \
    g[4]=mk2(c2.x,c2.y); g[5]=mk2(c2.z,c2.w); \
    g[6]=mk2(c3.x,c3.y); g[7]=mk2(c3.z,c3.w); \
    { f2 A2=splat2(A), B2=splat2(Bst); \
      _Pragma("unroll") for (int p=0;p<8;p++){ \
        g[p]=fma2(m0v[p],A2,g[p]); g[p]=fma2(m1v[p],B2,g[p]); } } \
    f2 rr[8]; \
    _Pragma("unroll") for (int p=0;p<8;p++){ \
      f2 ex = mk2(EXPG(g[p].x), EXPG(g[p].y)); \
      f2 dd = mk2(ex.x+1.f, ex.y+1.f); \
      rr[p] = mk2(__builtin_amdgcn_rcpf(dd.x), __builtin_amdgcn_rcpf(dd.y)); } \
    f2 ua=mk2(0.f,0.f), ub=mk2(0.f,0.f), uc=mk2(0.f,0.f), ud=mk2(0.f,0.f); \
    _Pragma("unroll") for (int p=0;p<4;p++){ ua=fma2(rr[p],n0v[p],ua); ub=fma2(rr[p],n1v[p],ub); } \
    _Pragma("unroll") for (int p=4;p<8;p++){ uc=fma2(rr[p],n0v[p],uc); ud=fma2(rr[p],n1v[p],ud); } \
    float u0=(ua.x+ua.y)+(uc.x+uc.y); \
    float u1=(ub.x+ub.y)+(ud.x+ud.y); \
    wave64_sum2(u0,u1); \
    float U0 = N0 + RD63(u0); \
    float U1 = N1 + RD63(u1); \
    A   = fmaf(CA, U0, OMA*A); \
    Bst = fmaf(CA, U1, OMA*Bst); \
    if (lane<10){ \
      float add = lane==0 ? SCL*U0 : lane==1 ? SCL*U1 : xs[(T)*8+lane-2]; \
      o = fmaf(OMA, o, ALPHA*add); \
      outb[(T)*10+lane]=o; } \
  }

  #pragma unroll 1
  for (int c=0; c<SEQ/CH; c++){
    const int t0 = c*CH;

    // ---- phase A: P for this chunk, one s-slice at a time (32 VGPRs live) --
    #pragma unroll 1
    for (int s=0;s<4;s++){
      f4 IvS[8];
      #pragma unroll
      for (int e=0;e<8;e++) IvS[e] = Ivl[s][e][lane];
      #pragma unroll 2
      for (int tt=0; tt<CH; tt++){
        f4 ya = ys4[t0+tt][0], yb = ys4[t0+tt][1];   // wave-uniform broadcast
        f4 acc =      IvS[0]*splat4(ya.x);
        acc = fma4(IvS[1], splat4(ya.y), acc);
        acc = fma4(IvS[2], splat4(ya.z), acc);
        acc = fma4(IvS[3], splat4(ya.w), acc);
        acc = fma4(IvS[4], splat4(yb.x), acc);
        acc = fma4(IvS[5], splat4(yb.y), acc);
        acc = fma4(IvS[6], splat4(yb.z), acc);
        acc = fma4(IvS[7], splat4(yb.w), acc);
        Pb[tt][s][lane] = acc;
      }
    }

    // ---- phase B: serial scan over the chunk (reads own lane's P back) ----
    f4 cA0=Pb[0][0][lane], cA1=Pb[0][1][lane], cA2=Pb[0][2][lane], cA3=Pb[0][3][lane];
    f4 cB0,cB1,cB2,cB3;
    #pragma unroll 1
    for (int tt=0; tt<CH; tt+=2){
      STEP(t0+tt,   tt+1,          cA0,cA1,cA2,cA3, cB0,cB1,cB2,cB3)
      STEP(t0+tt+1, (tt+2)&(CH-1), cB0,cB1,cB2,cB3, cA0,cA1,cA2,cA3)
    }
  }
  #undef STEP

  __syncthreads();
  const f4* ob4 = (const f4*)outb;
  f4* o4 = (f4*)out + (size_t)b*(SEQ*10/4);
  for (int idx=lane; idx<SEQ*10/4; idx+=64) o4[idx]=ob4[idx];
}

extern "C" void kernel_launch(void* const* d_in, const int* in_sizes, int n_in,
                              void* d_out, int out_size, void* d_ws, size_t ws_size,
                              hipStream_t stream) {
  const float* x     = (const float*)d_in[0];  // (64,512,8)
  const float* eps   = (const float*)d_in[1];  // (4,1024,12)
  const float* means = (const float*)d_in[2];  // (4,12)
  const float* tril  = (const float*)d_in[3];  // (4,12,12)
  const float* mw    = (const float*)d_in[4];  // (4,)
  float* out = (float*)d_out;                  // (64,512,10) fp32

  rnn_scan<<<NBAT, 64, 0, stream>>>(x, eps, means, tril, mw, out);
}

// Round 6
// 333.809 us; speedup vs baseline: 1.4510x; 1.4510x over previous
//
#include <hip/hip_runtime.h>

#define HS   1024
#define SEQ  512
#define NBAT 64
#define INSZ 8
#define NM   4
#define DD   12
#define CH   8      // steps per P-chunk (handoff granularity)

#define ALPHA 0.1f
#define OMA   0.9f
#define SCL   (500.0f/1024.0f)
#define AS    (ALPHA*SCL)

// exp(2h) as exp2(GS*h) when native exp2 exists. A, B, Yg all carry GS.
#if __has_builtin(__builtin_amdgcn_exp2f)
  #define GS 2.8853900817779268f      /* 2*log2(e) */
  #define EXPG(v) __builtin_amdgcn_exp2f(v)
#else
  #define GS 2.0f
  #define EXPG(v) __expf(v)
#endif

typedef float f2 __attribute__((ext_vector_type(2)));
typedef float f4 __attribute__((ext_vector_type(4)));
__device__ __forceinline__ f2 mk2(float a, float b){ f2 r; r.x=a; r.y=b; return r; }
__device__ __forceinline__ f2 splat2(float a){ return mk2(a,a); }
__device__ __forceinline__ f4 splat4(float a){ f4 r; r.x=a; r.y=a; r.z=a; r.w=a; return r; }
#if __has_builtin(__builtin_elementwise_fma)
__device__ __forceinline__ f2 fma2(f2 a, f2 b, f2 c){ return __builtin_elementwise_fma(a,b,c); }
__device__ __forceinline__ f4 fma4(f4 a, f4 b, f4 c){ return __builtin_elementwise_fma(a,b,c); }
#else
__device__ __forceinline__ f2 fma2(f2 a, f2 b, f2 c){
  f2 r; r.x=fmaf(a.x,b.x,c.x); r.y=fmaf(a.y,b.y,c.y); return r; }
__device__ __forceinline__ f4 fma4(f4 a, f4 b, f4 c){
  f4 r; r.x=fmaf(a.x,b.x,c.x); r.y=fmaf(a.y,b.y,c.y);
        r.z=fmaf(a.z,b.z,c.z); r.w=fmaf(a.w,b.w,c.w); return r; }
#endif

// DPP-based add: v += dpp_move(v). old=0 so masked/invalid lanes add 0.
#define DPP_ADD(v, ctrl, rmask, bmask) \
  v += __int_as_float(__builtin_amdgcn_update_dpp(0, __float_as_int(v), ctrl, rmask, bmask, true))

// Canonical gfx9 wave64 sum. Lane 63 holds the full 64-lane total afterwards.
__device__ __forceinline__ void wave64_sum2(float &a, float &b){
  DPP_ADD(a, 0x111, 0xf, 0xf); DPP_ADD(b, 0x111, 0xf, 0xf);  // row_shr:1
  DPP_ADD(a, 0x112, 0xf, 0xf); DPP_ADD(b, 0x112, 0xf, 0xf);  // row_shr:2
  DPP_ADD(a, 0x114, 0xf, 0xe); DPP_ADD(b, 0x114, 0xf, 0xe);  // row_shr:4
  DPP_ADD(a, 0x118, 0xf, 0xc); DPP_ADD(b, 0x118, 0xf, 0xc);  // row_shr:8
  DPP_ADD(a, 0x142, 0xa, 0xf); DPP_ADD(b, 0x142, 0xa, 0xf);  // row_bcast:15
  DPP_ADD(a, 0x143, 0xc, 0xf); DPP_ADD(b, 0x143, 0xc, 0xf);  // row_bcast:31
}
#define RD63(v) __int_as_float(__builtin_amdgcn_readlane(__float_as_int(v), 63))

// mixed[e] for unit i, e in [E0,E1)
template<int E0, int E1>
__device__ __forceinline__ void mix_unit(int i, const float* __restrict__ eps,
                                         const float* __restrict__ means,
                                         const float* __restrict__ tril,
                                         const float* w, float* outm){
  float ep[NM][DD];
  #pragma unroll
  for (int k=0;k<NM;k++){
    const float4* p = (const float4*)(eps + (size_t)(k*HS + i)*DD);
    float4 r0=p[0], r1=p[1], r2=p[2];
    ep[k][0]=r0.x; ep[k][1]=r0.y; ep[k][2]=r0.z; ep[k][3]=r0.w;
    ep[k][4]=r1.x; ep[k][5]=r1.y; ep[k][6]=r1.z; ep[k][7]=r1.w;
    ep[k][8]=r2.x; ep[k][9]=r2.y; ep[k][10]=r2.z; ep[k][11]=r2.w;
  }
  #pragma unroll
  for (int e=E0;e<E1;e++){
    float a = 0.f;
    #pragma unroll
    for (int k=0;k<NM;k++){
      float se = means[k*DD+e];
      #pragma unroll
      for (int d=0; d<e; d++) se = fmaf(ep[k][d], tril[(k*DD+e)*DD+d], se);
      float dg = fabsf(tril[(k*DD+e)*DD+e] - 1e-12f) + 1e-12f;
      se = fmaf(ep[k][e], dg, se);
      a = fmaf(w[k], se, a);
    }
    outm[e-E0] = a;
  }
}

// Producer/consumer, 2 waves per batch, chunk-granular LDS handoff.
// Wave 1 (producer): P[t][i] = I_i . Yg(t) into a double-buffered LDS chunk,
//   plus output columns 2..9 (pure x-EMA). Runs 1-2 chunks ahead.
// Wave 0 (consumer): the irreducible serial core (fold -> exp/rcp -> reduce ->
//   DPP -> A,B update), reading P with a 1-step ds_read prefetch.
// Sync: write-once counters in LDS, polled once per 8-step chunk (cross-wave
// LDS data-flag ordering validated in an earlier round). Waves land on
// different SIMDs -> producer issue does not steal consumer issue slots.
__global__ __launch_bounds__(128,1)
void rnn_scan(const float* __restrict__ x, const float* __restrict__ eps,
              const float* __restrict__ means, const float* __restrict__ tril,
              const float* __restrict__ mw, float* __restrict__ out)
{
  const int b    = blockIdx.x;
  const int tid  = threadIdx.x;
  const int wv   = tid >> 6;
  const int lane = tid & 63;

  __shared__ float xs[SEQ*INSZ];                 // 16 KB
  __shared__ f4    Pb[2][CH][4][64];             // 64 KB: double-buffered P
  __shared__ __align__(16) float outb[SEQ*10];   // 20 KB
  __shared__ int prod_ready, cons_done;          //  (total ~100 KB)

  // stage x[b] cooperatively (128 threads), init flags
  { const f4* xp=(const f4*)(x + (size_t)b*SEQ*INSZ);
    f4* xd=(f4*)xs;
    for (int idx=tid; idx<SEQ*INSZ/4; idx+=128) xd[idx]=xp[idx]; }
  if (tid==0){ prod_ready=0; cons_done=0; }

  float w[NM];
  { float s=0.f;
    #pragma unroll
    for (int k=0;k<NM;k++){ w[k]=fmaxf(mw[k],1e-6f); s+=w[k]; }
    float inv=1.0f/s;
    #pragma unroll
    for (int k=0;k<NM;k++) w[k]*=inv; }

  __syncthreads();   // xs + flags visible to both waves (only pre-loop barrier)

  volatile int* vpr = (volatile int*)&prod_ready;
  volatile int* vcd = (volatile int*)&cons_done;

  if (wv==1){
    // ======================= PRODUCER =======================
    // Iv[s][e] component j = mixed[4+e] of unit 16*lane+4*s+j
    f4 Iv[4][8];
    #pragma unroll
    for (int s=0;s<4;s++){
      #pragma unroll
      for (int j=0;j<4;j++){
        float mm[8];
        mix_unit<4,12>(16*lane + 4*s + j, eps, means, tril, w, mm);
        #pragma unroll
        for (int e=0;e<8;e++) Iv[s][e][j] = mm[e];
      }
    }

    const float AG = GS*ALPHA;
    float Yg[8];
    #pragma unroll
    for (int e=0;e<8;e++) Yg[e]=0.f;

    const bool olane = (lane>=8 && lane<16);   // lanes 8..15 own out cols 2..9
    const int  oc    = lane-8;
    float ox = 0.f;

    // prefetch x_0
    f4 xa = ((const f4*)xs)[0], xb = ((const f4*)xs)[1];
    float xo = olane ? xs[oc] : 0.f;

    #pragma unroll 1
    for (int c=0;c<SEQ/CH;c++){
      if (c>=2){ while (*vcd < c-1) __builtin_amdgcn_s_sleep(1); }
      #pragma unroll 2
      for (int tt=0;tt<CH;tt++){
        const int t = c*CH + tt;
        // P from Yg(t) (Yg BEFORE folding x_t -- verified order)
        #pragma unroll
        for (int s=0;s<4;s++){
          f4 acc =      Iv[s][0]*splat4(Yg[0]);
          acc = fma4(Iv[s][1], splat4(Yg[1]), acc);
          acc = fma4(Iv[s][2], splat4(Yg[2]), acc);
          acc = fma4(Iv[s][3], splat4(Yg[3]), acc);
          acc = fma4(Iv[s][4], splat4(Yg[4]), acc);
          acc = fma4(Iv[s][5], splat4(Yg[5]), acc);
          acc = fma4(Iv[s][6], splat4(Yg[6]), acc);
          acc = fma4(Iv[s][7], splat4(Yg[7]), acc);
          Pb[c&1][tt][s][lane] = acc;
        }
        // output columns 2..9: o = fma(OMA, o, ALPHA*x[t][col-2])
        if (olane){ ox = fmaf(OMA, ox, ALPHA*xo); outb[t*10 + oc + 2] = ox; }
        // fold x_t into Yg
        Yg[0]=fmaf(OMA,Yg[0],AG*xa.x); Yg[1]=fmaf(OMA,Yg[1],AG*xa.y);
        Yg[2]=fmaf(OMA,Yg[2],AG*xa.z); Yg[3]=fmaf(OMA,Yg[3],AG*xa.w);
        Yg[4]=fmaf(OMA,Yg[4],AG*xb.x); Yg[5]=fmaf(OMA,Yg[5],AG*xb.y);
        Yg[6]=fmaf(OMA,Yg[6],AG*xb.z); Yg[7]=fmaf(OMA,Yg[7],AG*xb.w);
        // prefetch x_{t+1} (latency hides under next step's MACs)
        if (t+1 < SEQ){
          xa = ((const f4*)xs)[(t+1)*2]; xb = ((const f4*)xs)[(t+1)*2+1];
          if (olane) xo = xs[(t+1)*8 + oc];
        }
      }
      asm volatile("" ::: "memory");       // data writes before flag
      if (lane==0) *vpr = c+1;
    }
  } else {
    // ======================= CONSUMER =======================
    // pairs p: units 16*lane+2p, 16*lane+2p+1 (matches producer P layout)
    f2 m0v[8], m1v[8], n0v[8], n1v[8];
    float sn0=0.f, sn1=0.f;
    #pragma unroll
    for (int p=0;p<8;p++){
      float mA[4], mB[4];
      mix_unit<0,4>(16*lane+2*p,   eps, means, tril, w, mA);
      mix_unit<0,4>(16*lane+2*p+1, eps, means, tril, w, mB);
      m0v[p]=mk2(mA[0],mB[0]); m1v[p]=mk2(mA[1],mB[1]);
      sn0 += mA[2]+mB[2];      sn1 += mA[3]+mB[3];
      n0v[p]=mk2(-2.f*mA[2], -2.f*mB[2]);
      n1v[p]=mk2(-2.f*mA[3], -2.f*mB[3]);
    }
    wave64_sum2(sn0, sn1);
    const float N0 = RD63(sn0), N1 = RD63(sn1);

    const float CA = GS*AS;
    float A=0.f, Bst=0.f, o=0.f;

  #define STEP(T, TN, buf, c0,c1,c2,c3, d0,d1,d2,d3) { \
    d0=Pb[buf][TN][0][lane]; d1=Pb[buf][TN][1][lane]; \
    d2=Pb[buf][TN][2][lane]; d3=Pb[buf][TN][3][lane]; \
    f2 g[8]; \
    g[0]=mk2(c0.x,c0.y); g[1]=mk2(c0.z,c0.w); \
    g[2]=mk2(c1.x,c1.y); g[3]=mk2(c1.z,c1.w); \
    g[4]=mk2(c2.x,c2.y); g[5]=mk2(c2.z,c2.w); \
    g[6]=mk2(c3.x,c3.y); g[7]=mk2(c3.z,c3.w); \
    { f2 A2=splat2(A), B2=splat2(Bst); \
      _Pragma("unroll") for (int p=0;p<8;p++){ \
        g[p]=fma2(m0v[p],A2,g[p]); g[p]=fma2(m1v[p],B2,g[p]); } } \
    f2 rr[8]; \
    _Pragma("unroll") for (int p=0;p<8;p++){ \
      f2 ex = mk2(EXPG(g[p].x), EXPG(g[p].y)); \
      f2 dd = mk2(ex.x+1.f, ex.y+1.f); \
      rr[p] = mk2(__builtin_amdgcn_rcpf(dd.x), __builtin_amdgcn_rcpf(dd.y)); } \
    f2 ua=mk2(0.f,0.f), ub=mk2(0.f,0.f), uc=mk2(0.f,0.f), ud=mk2(0.f,0.f); \
    _Pragma("unroll") for (int p=0;p<4;p++){ ua=fma2(rr[p],n0v[p],ua); ub=fma2(rr[p],n1v[p],ub); } \
    _Pragma("unroll") for (int p=4;p<8;p++){ uc=fma2(rr[p],n0v[p],uc); ud=fma2(rr[p],n1v[p],ud); } \
    float u0=(ua.x+ua.y)+(uc.x+uc.y); \
    float u1=(ub.x+ub.y)+(ud.x+ud.y); \
    wave64_sum2(u0,u1); \
    float U0 = N0 + RD63(u0); \
    float U1 = N1 + RD63(u1); \
    A   = fmaf(CA, U0, OMA*A); \
    Bst = fmaf(CA, U1, OMA*Bst); \
    if (lane<2){ \
      float add = lane==0 ? SCL*U0 : SCL*U1; \
      o = fmaf(OMA, o, ALPHA*add); \
      outb[(T)*10+lane]=o; } \
  }

    #pragma unroll 1
    for (int c=0;c<SEQ/CH;c++){
      while (*vpr < c+1) ;               // steady state: already satisfied
      asm volatile("" ::: "memory");     // no P reads hoisted above the poll
      const int buf = c&1;
      f4 cA0=Pb[buf][0][0][lane], cA1=Pb[buf][0][1][lane],
         cA2=Pb[buf][0][2][lane], cA3=Pb[buf][0][3][lane];
      f4 cB0,cB1,cB2,cB3;
      const int t0 = c*CH;
      #pragma unroll 1
      for (int tt=0; tt<CH; tt+=2){
        STEP(t0+tt,   tt+1,          buf, cA0,cA1,cA2,cA3, cB0,cB1,cB2,cB3)
        STEP(t0+tt+1, (tt+2)&(CH-1), buf, cB0,cB1,cB2,cB3, cA0,cA1,cA2,cA3)
      }
      asm volatile("" ::: "memory");     // P reads issued before flag
      if (lane==0) *vcd = c+1;
    }
  #undef STEP
  }

  __syncthreads();   // outb complete (both waves)
  const f4* ob4 = (const f4*)outb;
  f4* o4 = (f4*)out + (size_t)b*(SEQ*10/4);
  for (int idx=tid; idx<SEQ*10/4; idx+=128) o4[idx]=ob4[idx];
}

extern "C" void kernel_launch(void* const* d_in, const int* in_sizes, int n_in,
                              void* d_out, int out_size, void* d_ws, size_t ws_size,
                              hipStream_t stream) {
  const float* x     = (const float*)d_in[0];  // (64,512,8)
  const float* eps   = (const float*)d_in[1];  // (4,1024,12)
  const float* means = (const float*)d_in[2];  // (4,12)
  const float* tril  = (const float*)d_in[3];  // (4,12,12)
  const float* mw    = (const float*)d_in[4];  // (4,)
  float* out = (float*)d_out;                  // (64,512,10) fp32

  rnn_scan<<<NBAT, 128, 0, stream>>>(x, eps, means, tril, mw, out);
}

// Round 7
// 288.959 us; speedup vs baseline: 1.6762x; 1.1552x over previous
//
#include <hip/hip_runtime.h>

#define HS   1024
#define SEQ  512
#define NBAT 64
#define INSZ 8
#define NM   4
#define DD   12

#define ALPHA 0.1f
#define OMA   0.9f
#define SCL   (500.0f/1024.0f)
#define AS    (ALPHA*SCL)

// exp(2h) as exp2(hs) where hs = 2*log2(e)*h (state kept pre-scaled).
#if __has_builtin(__builtin_amdgcn_exp2f)
  #define GSC 2.8853900817779268f     /* 2*log2(e) */
  #define EXPG(v) __builtin_amdgcn_exp2f(v)
#else
  #define GSC 2.0f
  #define EXPG(v) __expf(v)
#endif

typedef float f2 __attribute__((ext_vector_type(2)));
typedef float f4 __attribute__((ext_vector_type(4)));
__device__ __forceinline__ f2 mk2(float a, float b){ f2 r; r.x=a; r.y=b; return r; }
__device__ __forceinline__ f2 splat2(float a){ return mk2(a,a); }
#if __has_builtin(__builtin_elementwise_fma)
__device__ __forceinline__ f2 fma2(f2 a, f2 b, f2 c){ return __builtin_elementwise_fma(a,b,c); }
#else
__device__ __forceinline__ f2 fma2(f2 a, f2 b, f2 c){
  f2 r; r.x=fmaf(a.x,b.x,c.x); r.y=fmaf(a.y,b.y,c.y); return r; }
#endif

// DPP-based add: v += dpp_move(v). old=0 so masked/invalid lanes add 0.
#define DPP_ADD(v, ctrl, rmask, bmask) \
  v += __int_as_float(__builtin_amdgcn_update_dpp(0, __float_as_int(v), ctrl, rmask, bmask, true))

// Canonical gfx9 wave64 sum. Lane 63 holds the full 64-lane total afterwards.
__device__ __forceinline__ void wave64_sum2(float &a, float &b){
  DPP_ADD(a, 0x111, 0xf, 0xf); DPP_ADD(b, 0x111, 0xf, 0xf);  // row_shr:1
  DPP_ADD(a, 0x112, 0xf, 0xf); DPP_ADD(b, 0x112, 0xf, 0xf);  // row_shr:2
  DPP_ADD(a, 0x114, 0xf, 0xe); DPP_ADD(b, 0x114, 0xf, 0xe);  // row_shr:4
  DPP_ADD(a, 0x118, 0xf, 0xc); DPP_ADD(b, 0x118, 0xf, 0xc);  // row_shr:8
  DPP_ADD(a, 0x142, 0xa, 0xf); DPP_ADD(b, 0x142, 0xa, 0xf);  // row_bcast:15
  DPP_ADD(a, 0x143, 0xc, 0xf); DPP_ADD(b, 0x143, 0xc, 0xf);  // row_bcast:31
}

// mixed[e] for unit i, e in [0,12)
__device__ __forceinline__ void mix_unit(int i, const float* __restrict__ eps,
                                         const float* __restrict__ means,
                                         const float* __restrict__ tril,
                                         const float* w, float* outm){
  float ep[NM][DD];
  #pragma unroll
  for (int k=0;k<NM;k++){
    const float4* p = (const float4*)(eps + (size_t)(k*HS + i)*DD);
    float4 r0=p[0], r1=p[1], r2=p[2];
    ep[k][0]=r0.x; ep[k][1]=r0.y; ep[k][2]=r0.z; ep[k][3]=r0.w;
    ep[k][4]=r1.x; ep[k][5]=r1.y; ep[k][6]=r1.z; ep[k][7]=r1.w;
    ep[k][8]=r2.x; ep[k][9]=r2.y; ep[k][10]=r2.z; ep[k][11]=r2.w;
  }
  #pragma unroll
  for (int e=0;e<DD;e++){
    float a = 0.f;
    #pragma unroll
    for (int k=0;k<NM;k++){
      float se = means[k*DD+e];
      #pragma unroll
      for (int d=0; d<e; d++) se = fmaf(ep[k][d], tril[(k*DD+e)*DD+d], se);
      float dg = fabsf(tril[(k*DD+e)*DD+e] - 1e-12f) + 1e-12f;
      se = fmaf(ep[k][e], dg, se);
      a = fmaf(w[k], se, a);
    }
    outm[e] = a;
  }
}

// Slim R0: 4 waves x 4 units/lane (trans pipe split 4-ways), one barrier/step.
// Cuts vs R0: GS-scaled state (exp2 direct), N-trick (U = N + sum(-2n * r)),
// f2-packed inj/accum/update, folded constants, 1-step x prefetch.
__global__ __launch_bounds__(256,1)
void rnn_scan(const float* __restrict__ x, const float* __restrict__ eps,
              const float* __restrict__ means, const float* __restrict__ tril,
              const float* __restrict__ mw, float* __restrict__ out)
{
  const int b    = blockIdx.x;
  const int tid  = threadIdx.x;
  const int wave = tid >> 6;
  const int lane = tid & 63;

  __shared__ float xs[SEQ*INSZ];                 // 16 KB
  __shared__ __align__(16) f2 red[2][4];         // double-buffered wave partials
  __shared__ __align__(16) float outb[SEQ*10];   // 20 KB

  // stage x[b] (coalesced f4, 256 threads)
  { const f4* xp=(const f4*)(x + (size_t)b*SEQ*INSZ);
    f4* xd=(f4*)xs;
    for (int idx=tid; idx<SEQ*INSZ/4; idx+=256) xd[idx]=xp[idx]; }

  float w[NM];
  { float s=0.f;
    #pragma unroll
    for (int k=0;k<NM;k++){ w[k]=fmaxf(mw[k],1e-6f); s+=w[k]; }
    float inv=1.0f/s;
    #pragma unroll
    for (int k=0;k<NM;k++) w[k]*=inv; }

  // ---- per-lane params: pair q holds units tid+(2q)*256, tid+(2q+1)*256 ----
  // m0g/m1g carry GSC*AS; n0v/n1v carry -2n; ALG = GSC*ALPHA folds into inj.
  f2 m0g[2], m1g[2], n0v[2], n1v[2], I2[2][8];
  float pn0=0.f, pn1=0.f;
  #pragma unroll
  for (int q=0;q<2;q++){
    #pragma unroll
    for (int c=0;c<2;c++){
      float mm[DD];
      mix_unit(tid + (2*q+c)*256, eps, means, tril, w, mm);
      if (c==0){ m0g[q].x=(GSC*AS)*mm[0]; m1g[q].x=(GSC*AS)*mm[1];
                 n0v[q].x=-2.f*mm[2];     n1v[q].x=-2.f*mm[3]; }
      else     { m0g[q].y=(GSC*AS)*mm[0]; m1g[q].y=(GSC*AS)*mm[1];
                 n0v[q].y=-2.f*mm[2];     n1v[q].y=-2.f*mm[3]; }
      pn0 += mm[2]; pn1 += mm[3];
      #pragma unroll
      for (int e=0;e<8;e++){
        if (c==0) I2[q][e].x = mm[4+e]; else I2[q][e].y = mm[4+e];
      }
    }
  }

  // ---- N0,N1 = sum of n over ALL 1024 units (one-time cross-wave reduce) ----
  wave64_sum2(pn0, pn1);
  if (lane==63) red[0][wave] = mk2(pn0,pn1);
  __syncthreads();
  f2 rN0=red[0][0], rN1=red[0][1], rN2=red[0][2], rN3=red[0][3];
  const float N0 = (rN0.x+rN1.x)+(rN2.x+rN3.x);
  const float N1 = (rN0.y+rN1.y)+(rN2.y+rN3.y);
  __syncthreads();   // red[0] consumed before step 0 overwrites it

  const float ALG = GSC*ALPHA;
  f2 hs[2]; hs[0]=mk2(0.f,0.f); hs[1]=mk2(0.f,0.f);
  float o = 0.f;

  const f4* xs4 = (const f4*)xs;
  f4 xa = xs4[0], xb = xs4[1];     // x_0 prefetched

  #pragma unroll 2
  for (int t=0;t<SEQ;t++){
    // r = rcp(exp2(hs)+1); partial u = sum(-2n * r)  (the only coupled part)
    float e0=EXPG(hs[0].x), e1=EXPG(hs[0].y), e2=EXPG(hs[1].x), e3=EXPG(hs[1].y);
    f2 rq0 = mk2(__builtin_amdgcn_rcpf(e0+1.f), __builtin_amdgcn_rcpf(e1+1.f));
    f2 rq1 = mk2(__builtin_amdgcn_rcpf(e2+1.f), __builtin_amdgcn_rcpf(e3+1.f));
    f2 s0 = rq0*n0v[0]; s0 = fma2(rq1, n0v[1], s0);
    f2 s1 = rq0*n1v[0]; s1 = fma2(rq1, n1v[1], s1);
    float u0 = s0.x+s0.y, u1 = s1.x+s1.y;
    wave64_sum2(u0,u1);                         // DPP butterfly, lane 63 total
    if (lane==63) red[t&1][wave] = mk2(u0,u1);

    // inj = x_t @ I^T (independent of u -- overlaps the DPP/barrier)
    f2 inj[2];
    #pragma unroll
    for (int q=0;q<2;q++){
      f2 a =      I2[q][0]*splat2(xa.x);
      a = fma2(I2[q][1], splat2(xa.y), a);
      a = fma2(I2[q][2], splat2(xa.z), a);
      a = fma2(I2[q][3], splat2(xa.w), a);
      a = fma2(I2[q][4], splat2(xb.x), a);
      a = fma2(I2[q][5], splat2(xb.y), a);
      a = fma2(I2[q][6], splat2(xb.z), a);
      a = fma2(I2[q][7], splat2(xb.w), a);
      inj[q]=a;
    }
    // prefetch x_{t+1} (wraps harmlessly at the final step)
    { const int tn = (t+1)&(SEQ-1); xa = xs4[tn*2]; xb = xs4[tn*2+1]; }

    __syncthreads();
    f2 r0=red[t&1][0], r1=red[t&1][1], r2=red[t&1][2], r3=red[t&1][3];
    const float U0 = N0 + ((r0.x+r1.x)+(r2.x+r3.x));
    const float U1 = N1 + ((r0.y+r1.y)+(r2.y+r3.y));

    { f2 U0s=splat2(U0), U1s=splat2(U1), OMs=splat2(OMA), ALs=splat2(ALG);
      #pragma unroll
      for (int q=0;q<2;q++){
        f2 acc = inj[q]*ALs;
        acc = fma2(m0g[q], U0s, acc);
        acc = fma2(m1g[q], U1s, acc);
        hs[q] = fma2(OMs, hs[q], acc);
      } }

    // o_t = pinv(span) @ h_t exactly (h lives in col(span), pinv@span = I_10)
    if (tid < 10){
      float add = (tid==0) ? SCL*U0 : (tid==1) ? SCL*U1 : xs[t*8 + tid-2];
      o = __builtin_fmaf(OMA, o, ALPHA*add);
      outb[t*10+tid] = o;
    }
  }

  __syncthreads();
  // burst-dump staged outputs, coalesced float4
  const f4* ob4 = (const f4*)outb;
  f4* o4 = (f4*)out + (size_t)b*(SEQ*10/4);
  for (int idx=tid; idx<SEQ*10/4; idx+=256) o4[idx]=ob4[idx];
}

extern "C" void kernel_launch(void* const* d_in, const int* in_sizes, int n_in,
                              void* d_out, int out_size, void* d_ws, size_t ws_size,
                              hipStream_t stream) {
  const float* x     = (const float*)d_in[0];  // (64,512,8)
  const float* eps   = (const float*)d_in[1];  // (4,1024,12)
  const float* means = (const float*)d_in[2];  // (4,12)
  const float* tril  = (const float*)d_in[3];  // (4,12,12)
  const float* mw    = (const float*)d_in[4];  // (4,)
  float* out = (float*)d_out;                  // (64,512,10) fp32

  rnn_scan<<<NBAT, 256, 0, stream>>>(x, eps, means, tril, mw, out);
}